// Round 6
// baseline (1429.199 us; speedup 1.0000x reference)
//
#include <hip/hip_runtime.h>

#define B_   16
#define C_   64
#define HW_  65536
#define CHW_ (C_ * HW_)   // 4194304 elements per batch
#define NT_  64           // n-tile per k1 step

__device__ __forceinline__ float comp4(float4 v, int i) {
    return i == 0 ? v.x : i == 1 ? v.y : i == 2 ? v.z : v.w;
}

// ---------------------------------------------------------------------------
// Kernel 1 v3: partial Gram.  S[b,c,d] = sum_n X[b,c*HW+n] * Xflat[b,n*64+d]
// Async-STAGE split: tile t+1's global loads issued into registers BEFORE
// compute of tile t (unroll-2 ping-pong reg sets, static indexing); reg->LDS
// write after the barrier.  Staging latency hides under the compute phase.
// ---------------------------------------------------------------------------
__global__ __launch_bounds__(256, 3) void k1_gram(const float* __restrict__ x,
                                                  float* __restrict__ partial,
                                                  int nch, int nb) {
    const int ch   = blockIdx.x;
    const int b    = blockIdx.y;
    const int t    = threadIdx.x;
    const int w    = t >> 6;
    const int lane = t & 63;
    const int si   = lane >> 3;
    const int sj   = lane & 7;

    __shared__ float QsT[NT_][68];      // [n_local][c], pad 68
    __shared__ float Ks[NT_ * C_];      // [n_local][d] natural, flat

    float4 acc[8][2];
    #pragma unroll
    for (int r = 0; r < 8; r++) {
        acc[r][0] = make_float4(0.f, 0.f, 0.f, 0.f);
        acc[r][1] = make_float4(0.f, 0.f, 0.f, 0.f);
    }

    const float* xb = x + (size_t)b * CHW_;
    const int nA = t & 63;
    const int cq = t >> 6;

#define K1_LOAD(Rq, Rk, nt)                                               \
    {                                                                     \
        _Pragma("unroll")                                                 \
        for (int p = 0; p < 4; p++) {                                     \
            const int c = 4 * (cq + 4 * p);                               \
            const float* qp = xb + (size_t)c * HW_ + (nt) + nA;           \
            Rq[p].x = qp[0];                                              \
            Rq[p].y = qp[(size_t)1 * HW_];                                \
            Rq[p].z = qp[(size_t)2 * HW_];                                \
            Rq[p].w = qp[(size_t)3 * HW_];                                \
        }                                                                 \
        const float* kp = xb + (size_t)(nt) * C_;                         \
        _Pragma("unroll")                                                 \
        for (int p = 0; p < 4; p++)                                       \
            Rk[p] = *(const float4*)(kp + 4 * t + 1024 * p);              \
    }

#define K1_WRITE(Rq, Rk)                                                  \
    {                                                                     \
        _Pragma("unroll")                                                 \
        for (int p = 0; p < 4; p++)                                       \
            *(float4*)&QsT[nA][4 * (cq + 4 * p)] = Rq[p];                 \
        _Pragma("unroll")                                                 \
        for (int p = 0; p < 4; p++)                                       \
            *(float4*)&Ks[4 * t + 1024 * p] = Rk[p];                      \
    }

#define K1_COMPUTE()                                                      \
    {                                                                     \
        _Pragma("unroll")                                                 \
        for (int kk2 = 0; kk2 < 16; kk2++) {                              \
            const int kk = 16 * w + kk2;                                  \
            const float4 q0  = *(const float4*)&QsT[kk][8 * si];          \
            const float4 q1  = *(const float4*)&QsT[kk][8 * si + 4];      \
            const float4 k0  = *(const float4*)&Ks[kk * C_ + 8 * sj];     \
            const float4 k1v = *(const float4*)&Ks[kk * C_ + 8 * sj + 4]; \
            _Pragma("unroll")                                             \
            for (int r = 0; r < 8; r++) {                                 \
                const float qv = (r < 4) ? comp4(q0, r) : comp4(q1, r - 4); \
                acc[r][0].x += qv * k0.x;                                 \
                acc[r][0].y += qv * k0.y;                                 \
                acc[r][0].z += qv * k0.z;                                 \
                acc[r][0].w += qv * k0.w;                                 \
                acc[r][1].x += qv * k1v.x;                                \
                acc[r][1].y += qv * k1v.y;                                \
                acc[r][1].z += qv * k1v.z;                                \
                acc[r][1].w += qv * k1v.w;                                \
            }                                                             \
        }                                                                 \
    }

    float4 Aq[4], Ak[4], Bq[4], Bk[4];
    const int t0    = ch * nb;
    const int ntile = nb / NT_;        // HW/(nch*64): power of 2, >= 2, even

    K1_LOAD(Aq, Ak, t0);
    for (int it = 0; it < ntile; it += 2) {
        __syncthreads();               // LDS free (previous compute done)
        K1_WRITE(Aq, Ak);
        __syncthreads();
        K1_LOAD(Bq, Bk, t0 + (it + 1) * NT_);   // overlaps compute of tile it
        K1_COMPUTE();
        __syncthreads();
        K1_WRITE(Bq, Bk);
        __syncthreads();
        if (it + 2 < ntile) K1_LOAD(Aq, Ak, t0 + (it + 2) * NT_);
        K1_COMPUTE();
    }
#undef K1_LOAD
#undef K1_WRITE
#undef K1_COMPUTE

    __syncthreads();
    float* sred = Ks;
    for (int wr = 0; wr < 4; wr++) {
        if (w == wr) {
            #pragma unroll
            for (int r = 0; r < 8; r++) {
                const int idx = (8 * si + r) * 64 + 8 * sj;
                if (wr == 0) {
                    *(float4*)&sred[idx]     = acc[r][0];
                    *(float4*)&sred[idx + 4] = acc[r][1];
                } else {
                    float4 v0 = *(float4*)&sred[idx];
                    float4 v1 = *(float4*)&sred[idx + 4];
                    v0.x += acc[r][0].x; v0.y += acc[r][0].y;
                    v0.z += acc[r][0].z; v0.w += acc[r][0].w;
                    v1.x += acc[r][1].x; v1.y += acc[r][1].y;
                    v1.z += acc[r][1].z; v1.w += acc[r][1].w;
                    *(float4*)&sred[idx]     = v0;
                    *(float4*)&sred[idx + 4] = v1;
                }
            }
        }
        __syncthreads();
    }

    float* pb = partial + (size_t)(b * nch + ch) * 4096;
    for (int i = 4 * t; i < 4096; i += 1024)
        *(float4*)&pb[i] = *(const float4*)&sred[i];
}

// ---------------------------------------------------------------------------
// Kernel 2 v2: reduce partials + softmax (unchanged).
// Writes Mt[b,d,c] = softmax(S)[b,c,d] + (c==d).
// ---------------------------------------------------------------------------
__global__ __launch_bounds__(256) void k2_softmax(const float* __restrict__ partial,
                                                  float* __restrict__ mt, int nch) {
    const int c = blockIdx.x;
    const int b = blockIdx.y;
    const int t = threadIdx.x;
    const int w = t >> 6;
    const int d = t & 63;

    float s = 0.f;
    for (int ch = w; ch < nch; ch += 4)
        s += partial[(size_t)(b * nch + ch) * 4096 + c * 64 + d];

    __shared__ float red[256];
    red[t] = s;
    __syncthreads();
    if (w == 0) {
        s = red[d] + red[64 + d] + red[128 + d] + red[192 + d];
        float m = s;
        #pragma unroll
        for (int off = 32; off > 0; off >>= 1) m = fmaxf(m, __shfl_xor(m, off));
        const float e = expf(s - m);
        float sum = e;
        #pragma unroll
        for (int off = 32; off > 0; off >>= 1) sum += __shfl_xor(sum, off);
        mt[(size_t)b * 4096 + d * 64 + c] = e / sum + (c == d ? 1.f : 0.f);
    }
}

// ---------------------------------------------------------------------------
// Kernel 3 v5: out[b,c,n] = sum_d Mt[b,d,c] * X[b, d*HW + n]
// x: rolling 8-deep register prefetch (covers ~900cy HBM latency).
// M: staged in LDS once, then explicit 1-deep ping-pong register prefetch
// (ds_read broadcast, ~120cy latency covered by 64 FMA instrs of the
// previous d).  Unroll-2 d-loop, all static indexing.
// ---------------------------------------------------------------------------
__global__ __launch_bounds__(256, 3) void k3_out(const float* __restrict__ x,
                                                 const float* __restrict__ mt,
                                                 float* __restrict__ out) {
    const int nb   = blockIdx.x;
    const int b    = blockIdx.y;
    const int t    = threadIdx.x;
    const int w    = t >> 6;
    const int lane = t & 63;

    __shared__ float Ms[64 * 64];   // Mt[d][c]
    {
        const float* mg = mt + (size_t)b * 4096;
        for (int i = 4 * t; i < 4096; i += 1024)
            *(float4*)&Ms[i] = *(const float4*)&mg[i];
    }
    __syncthreads();

    const int c0 = 16 * w;
    const size_t nbase = (size_t)nb * 256 + 4 * lane;
    const float* xp = x + (size_t)b * CHW_ + nbase;

    float4 acc[16];
    #pragma unroll
    for (int r = 0; r < 16; r++) acc[r] = make_float4(0.f, 0.f, 0.f, 0.f);

    float4 xbuf[8];
    #pragma unroll
    for (int i = 0; i < 8; i++)
        xbuf[i] = *(const float4*)(xp + (size_t)i * HW_);

#define K3_LDM(M, dd)                                                     \
    {                                                                     \
        M[0] = *(const float4*)&Ms[(dd) * 64 + c0];                       \
        M[1] = *(const float4*)&Ms[(dd) * 64 + c0 + 4];                   \
        M[2] = *(const float4*)&Ms[(dd) * 64 + c0 + 8];                   \
        M[3] = *(const float4*)&Ms[(dd) * 64 + c0 + 12];                  \
    }

#define K3_FMA(M, xv)                                                     \
    _Pragma("unroll")                                                     \
    for (int g = 0; g < 4; g++) {                                         \
        _Pragma("unroll")                                                 \
        for (int r = 0; r < 4; r++) {                                     \
            const float mv = comp4(M[g], r);                              \
            acc[4 * g + r].x += mv * (xv).x;                              \
            acc[4 * g + r].y += mv * (xv).y;                              \
            acc[4 * g + r].z += mv * (xv).z;                              \
            acc[4 * g + r].w += mv * (xv).w;                              \
        }                                                                 \
    }

    float4 mA[4], mB[4];
    K3_LDM(mA, 0);

    #pragma unroll
    for (int d = 0; d < 64; d += 2) {
        K3_LDM(mB, d + 1);                  // prefetch next-d M (LDS)
        {
            const float4 xv = xbuf[d & 7];
            if (d + 8 < 64)
                xbuf[d & 7] = *(const float4*)(xp + (size_t)(d + 8) * HW_);
            K3_FMA(mA, xv);
        }
        if (d + 2 < 64) K3_LDM(mA, d + 2);  // prefetch d+2 M
        {
            const float4 xv = xbuf[(d + 1) & 7];
            if (d + 9 < 64)
                xbuf[(d + 1) & 7] = *(const float4*)(xp + (size_t)(d + 9) * HW_);
            K3_FMA(mB, xv);
        }
    }
#undef K3_LDM
#undef K3_FMA

    #pragma unroll
    for (int r = 0; r < 16; r++)
        *(float4*)(out + (size_t)b * CHW_ + (size_t)(c0 + r) * HW_ + nbase) = acc[r];
}

// ---------------------------------------------------------------------------
extern "C" void kernel_launch(void* const* d_in, const int* in_sizes, int n_in,
                              void* d_out, int out_size, void* d_ws, size_t ws_size,
                              hipStream_t stream) {
    const float* x = (const float*)d_in[0];
    float* out = (float*)d_out;

    float* wsf     = (float*)d_ws;
    float* mt      = wsf;                          // B*4096 floats
    float* partial = wsf + (size_t)B_ * 4096;      // B*nch*4096 floats

    int nch = 128;
    while (nch > 1) {
        size_t need = (size_t)B_ * 4096 * sizeof(float)
                    + (size_t)B_ * nch * 4096 * sizeof(float);
        if (need <= ws_size) break;
        nch >>= 1;
    }
    const int nb = HW_ / nch;

    k1_gram<<<dim3(nch, B_), 256, 0, stream>>>(x, partial, nch, nb);
    k2_softmax<<<dim3(C_, B_), 256, 0, stream>>>(partial, mt, nch);
    k3_out<<<dim3(HW_ / 256, B_), 256, 0, stream>>>(x, mt, out);
}

// Round 7
// 274.302 us; speedup vs baseline: 5.2103x; 5.2103x over previous
//
#include <hip/hip_runtime.h>

#define B_   16
#define C_   64
#define HW_  65536
#define CHW_ (C_ * HW_)   // 4194304 elements per batch
#define NT_  64           // n-tile per k1 step

__device__ __forceinline__ float comp4(float4 v, int i) {
    return i == 0 ? v.x : i == 1 ? v.y : i == 2 ? v.z : v.w;
}

// ---------------------------------------------------------------------------
// Kernel 1 v2 (reverted to round-2 version; the R6 async-stage rewrite
// spilled registers to scratch: WRITE_SIZE 2.76GB, 10x slowdown).
// S[b,c,d] = sum_n X[b,c*HW+n] * Xflat[b,n*64+d]
// ---------------------------------------------------------------------------
__global__ __launch_bounds__(256, 4) void k1_gram(const float* __restrict__ x,
                                                  float* __restrict__ partial,
                                                  int nch, int nb) {
    const int ch   = blockIdx.x;
    const int b    = blockIdx.y;
    const int t    = threadIdx.x;
    const int w    = t >> 6;
    const int lane = t & 63;
    const int si   = lane >> 3;
    const int sj   = lane & 7;

    __shared__ float QsT[NT_][68];      // [n_local][c], pad 68
    __shared__ float Ks[NT_ * C_];      // [n_local][d] natural, flat

    float4 acc[8][2];
    #pragma unroll
    for (int r = 0; r < 8; r++) {
        acc[r][0] = make_float4(0.f, 0.f, 0.f, 0.f);
        acc[r][1] = make_float4(0.f, 0.f, 0.f, 0.f);
    }

    const float* xb = x + (size_t)b * CHW_;
    const int nA = t & 63;
    const int cq = t >> 6;

    for (int nt = ch * nb; nt < ch * nb + nb; nt += NT_) {
        __syncthreads();

        #pragma unroll
        for (int p = 0; p < 4; p++) {
            const int c = 4 * (cq + 4 * p);
            const float* qp = xb + (size_t)c * HW_ + nt + nA;
            float4 v;
            v.x = qp[0];
            v.y = qp[(size_t)1 * HW_];
            v.z = qp[(size_t)2 * HW_];
            v.w = qp[(size_t)3 * HW_];
            *(float4*)&QsT[nA][c] = v;
        }
        const float* kp = xb + (size_t)nt * C_;
        #pragma unroll
        for (int p = 0; p < 4; p++) {
            const int f = 4 * t + 1024 * p;
            *(float4*)&Ks[f] = *(const float4*)(kp + f);
        }
        __syncthreads();

        #pragma unroll
        for (int kk2 = 0; kk2 < 16; kk2++) {
            const int kk = 16 * w + kk2;
            const float4 q0  = *(const float4*)&QsT[kk][8 * si];
            const float4 q1  = *(const float4*)&QsT[kk][8 * si + 4];
            const float4 k0  = *(const float4*)&Ks[kk * C_ + 8 * sj];
            const float4 k1v = *(const float4*)&Ks[kk * C_ + 8 * sj + 4];
            #pragma unroll
            for (int r = 0; r < 8; r++) {
                const float qv = (r < 4) ? comp4(q0, r) : comp4(q1, r - 4);
                acc[r][0].x += qv * k0.x;
                acc[r][0].y += qv * k0.y;
                acc[r][0].z += qv * k0.z;
                acc[r][0].w += qv * k0.w;
                acc[r][1].x += qv * k1v.x;
                acc[r][1].y += qv * k1v.y;
                acc[r][1].z += qv * k1v.z;
                acc[r][1].w += qv * k1v.w;
            }
        }
    }

    __syncthreads();
    float* sred = Ks;
    for (int wr = 0; wr < 4; wr++) {
        if (w == wr) {
            #pragma unroll
            for (int r = 0; r < 8; r++) {
                const int idx = (8 * si + r) * 64 + 8 * sj;
                if (wr == 0) {
                    *(float4*)&sred[idx]     = acc[r][0];
                    *(float4*)&sred[idx + 4] = acc[r][1];
                } else {
                    float4 v0 = *(float4*)&sred[idx];
                    float4 v1 = *(float4*)&sred[idx + 4];
                    v0.x += acc[r][0].x; v0.y += acc[r][0].y;
                    v0.z += acc[r][0].z; v0.w += acc[r][0].w;
                    v1.x += acc[r][1].x; v1.y += acc[r][1].y;
                    v1.z += acc[r][1].z; v1.w += acc[r][1].w;
                    *(float4*)&sred[idx]     = v0;
                    *(float4*)&sred[idx + 4] = v1;
                }
            }
        }
        __syncthreads();
    }

    float* pb = partial + (size_t)(b * nch + ch) * 4096;
    for (int i = 4 * t; i < 4096; i += 1024)
        *(float4*)&pb[i] = *(const float4*)&sred[i];
}

// ---------------------------------------------------------------------------
// Kernel 2 v2: reduce partials + softmax (unchanged).
// Writes Mt[b,d,c] = softmax(S)[b,c,d] + (c==d).
// ---------------------------------------------------------------------------
__global__ __launch_bounds__(256) void k2_softmax(const float* __restrict__ partial,
                                                  float* __restrict__ mt, int nch) {
    const int c = blockIdx.x;
    const int b = blockIdx.y;
    const int t = threadIdx.x;
    const int w = t >> 6;
    const int d = t & 63;

    float s = 0.f;
    for (int ch = w; ch < nch; ch += 4)
        s += partial[(size_t)(b * nch + ch) * 4096 + c * 64 + d];

    __shared__ float red[256];
    red[t] = s;
    __syncthreads();
    if (w == 0) {
        s = red[d] + red[64 + d] + red[128 + d] + red[192 + d];
        float m = s;
        #pragma unroll
        for (int off = 32; off > 0; off >>= 1) m = fmaxf(m, __shfl_xor(m, off));
        const float e = expf(s - m);
        float sum = e;
        #pragma unroll
        for (int off = 32; off > 0; off >>= 1) sum += __shfl_xor(sum, off);
        mt[(size_t)b * 4096 + d * 64 + c] = e / sum + (c == d ? 1.f : 0.f);
    }
}

// ---------------------------------------------------------------------------
// Kernel 3 v5 (unchanged from round 6 — measured ~115us):
// out[b,c,n] = sum_d Mt[b,d,c] * X[b, d*HW + n]
// x: rolling 8-deep register prefetch.  M: LDS broadcast with 1-deep
// ping-pong register prefetch.  Unroll-2 d-loop, all static indexing.
// ---------------------------------------------------------------------------
__global__ __launch_bounds__(256, 3) void k3_out(const float* __restrict__ x,
                                                 const float* __restrict__ mt,
                                                 float* __restrict__ out) {
    const int nb   = blockIdx.x;
    const int b    = blockIdx.y;
    const int t    = threadIdx.x;
    const int w    = t >> 6;
    const int lane = t & 63;

    __shared__ float Ms[64 * 64];   // Mt[d][c]
    {
        const float* mg = mt + (size_t)b * 4096;
        for (int i = 4 * t; i < 4096; i += 1024)
            *(float4*)&Ms[i] = *(const float4*)&mg[i];
    }
    __syncthreads();

    const int c0 = 16 * w;
    const size_t nbase = (size_t)nb * 256 + 4 * lane;
    const float* xp = x + (size_t)b * CHW_ + nbase;

    float4 acc[16];
    #pragma unroll
    for (int r = 0; r < 16; r++) acc[r] = make_float4(0.f, 0.f, 0.f, 0.f);

    float4 xbuf[8];
    #pragma unroll
    for (int i = 0; i < 8; i++)
        xbuf[i] = *(const float4*)(xp + (size_t)i * HW_);

#define K3_LDM(M, dd)                                                     \
    {                                                                     \
        M[0] = *(const float4*)&Ms[(dd) * 64 + c0];                       \
        M[1] = *(const float4*)&Ms[(dd) * 64 + c0 + 4];                   \
        M[2] = *(const float4*)&Ms[(dd) * 64 + c0 + 8];                   \
        M[3] = *(const float4*)&Ms[(dd) * 64 + c0 + 12];                  \
    }

#define K3_FMA(M, xv)                                                     \
    _Pragma("unroll")                                                     \
    for (int g = 0; g < 4; g++) {                                         \
        _Pragma("unroll")                                                 \
        for (int r = 0; r < 4; r++) {                                     \
            const float mv = comp4(M[g], r);                              \
            acc[4 * g + r].x += mv * (xv).x;                              \
            acc[4 * g + r].y += mv * (xv).y;                              \
            acc[4 * g + r].z += mv * (xv).z;                              \
            acc[4 * g + r].w += mv * (xv).w;                              \
        }                                                                 \
    }

    float4 mA[4], mB[4];
    K3_LDM(mA, 0);

    #pragma unroll
    for (int d = 0; d < 64; d += 2) {
        K3_LDM(mB, d + 1);                  // prefetch next-d M (LDS)
        {
            const float4 xv = xbuf[d & 7];
            if (d + 8 < 64)
                xbuf[d & 7] = *(const float4*)(xp + (size_t)(d + 8) * HW_);
            K3_FMA(mA, xv);
        }
        if (d + 2 < 64) K3_LDM(mA, d + 2);  // prefetch d+2 M
        {
            const float4 xv = xbuf[(d + 1) & 7];
            if (d + 9 < 64)
                xbuf[(d + 1) & 7] = *(const float4*)(xp + (size_t)(d + 9) * HW_);
            K3_FMA(mB, xv);
        }
    }
#undef K3_LDM
#undef K3_FMA

    #pragma unroll
    for (int r = 0; r < 16; r++)
        *(float4*)(out + (size_t)b * CHW_ + (size_t)(c0 + r) * HW_ + nbase) = acc[r];
}

// ---------------------------------------------------------------------------
extern "C" void kernel_launch(void* const* d_in, const int* in_sizes, int n_in,
                              void* d_out, int out_size, void* d_ws, size_t ws_size,
                              hipStream_t stream) {
    const float* x = (const float*)d_in[0];
    float* out = (float*)d_out;

    float* wsf     = (float*)d_ws;
    float* mt      = wsf;                          // B*4096 floats
    float* partial = wsf + (size_t)B_ * 4096;      // B*nch*4096 floats

    int nch = 128;
    while (nch > 1) {
        size_t need = (size_t)B_ * 4096 * sizeof(float)
                    + (size_t)B_ * nch * 4096 * sizeof(float);
        if (need <= ws_size) break;
        nch >>= 1;
    }
    const int nb = HW_ / nch;

    k1_gram<<<dim3(nch, B_), 256, 0, stream>>>(x, partial, nch, nb);
    k2_softmax<<<dim3(C_, B_), 256, 0, stream>>>(partial, mt, nch);
    k3_out<<<dim3(HW_ / 256, B_), 256, 0, stream>>>(x, mt, out);
}

// Round 8
// 261.893 us; speedup vs baseline: 5.4572x; 1.0474x over previous
//
#include <hip/hip_runtime.h>

#define B_   16
#define C_   64
#define HW_  65536
#define CHW_ (C_ * HW_)   // 4194304 elements per batch
#define NT_  64           // n-tile per k1 step

typedef short bf16x8 __attribute__((ext_vector_type(8)));
typedef float f32x4v __attribute__((ext_vector_type(4)));

__device__ __forceinline__ float comp4(float4 v, int i) {
    return i == 0 ? v.x : i == 1 ? v.y : i == 2 ? v.z : v.w;
}

// fp32 -> bf16 with round-to-nearest-even (values are finite, ~N(0,1) scale)
__device__ __forceinline__ unsigned short bfrne(float f) {
    unsigned int u = __float_as_uint(f);
    u += 0x7FFFu + ((u >> 16) & 1u);
    return (unsigned short)(u >> 16);
}

// ---------------------------------------------------------------------------
// Kernel 1 v2 (proven round-2 version, unchanged).
// S[b,c,d] = sum_n X[b,c*HW+n] * Xflat[b,n*64+d]
// ---------------------------------------------------------------------------
__global__ __launch_bounds__(256, 4) void k1_gram(const float* __restrict__ x,
                                                  float* __restrict__ partial,
                                                  int nch, int nb) {
    const int ch   = blockIdx.x;
    const int b    = blockIdx.y;
    const int t    = threadIdx.x;
    const int w    = t >> 6;
    const int lane = t & 63;
    const int si   = lane >> 3;
    const int sj   = lane & 7;

    __shared__ float QsT[NT_][68];      // [n_local][c], pad 68
    __shared__ float Ks[NT_ * C_];      // [n_local][d] natural, flat

    float4 acc[8][2];
    #pragma unroll
    for (int r = 0; r < 8; r++) {
        acc[r][0] = make_float4(0.f, 0.f, 0.f, 0.f);
        acc[r][1] = make_float4(0.f, 0.f, 0.f, 0.f);
    }

    const float* xb = x + (size_t)b * CHW_;
    const int nA = t & 63;
    const int cq = t >> 6;

    for (int nt = ch * nb; nt < ch * nb + nb; nt += NT_) {
        __syncthreads();

        #pragma unroll
        for (int p = 0; p < 4; p++) {
            const int c = 4 * (cq + 4 * p);
            const float* qp = xb + (size_t)c * HW_ + nt + nA;
            float4 v;
            v.x = qp[0];
            v.y = qp[(size_t)1 * HW_];
            v.z = qp[(size_t)2 * HW_];
            v.w = qp[(size_t)3 * HW_];
            *(float4*)&QsT[nA][c] = v;
        }
        const float* kp = xb + (size_t)nt * C_;
        #pragma unroll
        for (int p = 0; p < 4; p++) {
            const int f = 4 * t + 1024 * p;
            *(float4*)&Ks[f] = *(const float4*)(kp + f);
        }
        __syncthreads();

        #pragma unroll
        for (int kk2 = 0; kk2 < 16; kk2++) {
            const int kk = 16 * w + kk2;
            const float4 q0  = *(const float4*)&QsT[kk][8 * si];
            const float4 q1  = *(const float4*)&QsT[kk][8 * si + 4];
            const float4 k0  = *(const float4*)&Ks[kk * C_ + 8 * sj];
            const float4 k1v = *(const float4*)&Ks[kk * C_ + 8 * sj + 4];
            #pragma unroll
            for (int r = 0; r < 8; r++) {
                const float qv = (r < 4) ? comp4(q0, r) : comp4(q1, r - 4);
                acc[r][0].x += qv * k0.x;
                acc[r][0].y += qv * k0.y;
                acc[r][0].z += qv * k0.z;
                acc[r][0].w += qv * k0.w;
                acc[r][1].x += qv * k1v.x;
                acc[r][1].y += qv * k1v.y;
                acc[r][1].z += qv * k1v.z;
                acc[r][1].w += qv * k1v.w;
            }
        }
    }

    __syncthreads();
    float* sred = Ks;
    for (int wr = 0; wr < 4; wr++) {
        if (w == wr) {
            #pragma unroll
            for (int r = 0; r < 8; r++) {
                const int idx = (8 * si + r) * 64 + 8 * sj;
                if (wr == 0) {
                    *(float4*)&sred[idx]     = acc[r][0];
                    *(float4*)&sred[idx + 4] = acc[r][1];
                } else {
                    float4 v0 = *(float4*)&sred[idx];
                    float4 v1 = *(float4*)&sred[idx + 4];
                    v0.x += acc[r][0].x; v0.y += acc[r][0].y;
                    v0.z += acc[r][0].z; v0.w += acc[r][0].w;
                    v1.x += acc[r][1].x; v1.y += acc[r][1].y;
                    v1.z += acc[r][1].z; v1.w += acc[r][1].w;
                    *(float4*)&sred[idx]     = v0;
                    *(float4*)&sred[idx + 4] = v1;
                }
            }
        }
        __syncthreads();
    }

    float* pb = partial + (size_t)(b * nch + ch) * 4096;
    for (int i = 4 * t; i < 4096; i += 1024)
        *(float4*)&pb[i] = *(const float4*)&sred[i];
}

// ---------------------------------------------------------------------------
// Kernel 2 v3: reduce partials + softmax.
// Writes mbf[b,c,d] = bf16( softmax(S)[b,c,d] + (c==d) )  (A-operand layout).
// ---------------------------------------------------------------------------
__global__ __launch_bounds__(256) void k2_softmax(const float* __restrict__ partial,
                                                  unsigned short* __restrict__ mbf,
                                                  int nch) {
    const int c = blockIdx.x;
    const int b = blockIdx.y;
    const int t = threadIdx.x;
    const int w = t >> 6;
    const int d = t & 63;

    float s = 0.f;
    for (int ch = w; ch < nch; ch += 4)
        s += partial[(size_t)(b * nch + ch) * 4096 + c * 64 + d];

    __shared__ float red[256];
    red[t] = s;
    __syncthreads();
    if (w == 0) {
        s = red[d] + red[64 + d] + red[128 + d] + red[192 + d];
        float m = s;
        #pragma unroll
        for (int off = 32; off > 0; off >>= 1) m = fmaxf(m, __shfl_xor(m, off));
        const float e = expf(s - m);
        float sum = e;
        #pragma unroll
        for (int off = 32; off > 0; off >>= 1) sum += __shfl_xor(sum, off);
        mbf[(size_t)b * 4096 + c * 64 + d] = bfrne(e / sum + (c == d ? 1.f : 0.f));
    }
}

// ---------------------------------------------------------------------------
// Kernel 3 v6 (MFMA bf16): out[b,c,n] = sum_d M[c,d] * X[b, d*HW + n]
// No LDS.  Each wave owns a 64c x 64n tile independently (no barriers).
// A-frags (M, L2-hot): 8x dwordx4 direct loads, fragment layout
//   A[row=l%16][k=8*(l>>4)+j+32*ks] from mbf[c][d].
// B-frags: per-lane direct global dword loads in fragment layout
//   B[k=d][col=n]: lane reads X[(8*(l>>4)+j+32*ks)*HW + n0+16*nt+(l&15)],
// converted fp32->bf16 RNE in-register.  2 MFMA K-steps cover d=0..63.
// D[row][col]: col=lane&15, row=4*(lane>>4)+reg (m89-verified).
// ---------------------------------------------------------------------------
__global__ __launch_bounds__(256, 3) void k3_out(const float* __restrict__ x,
                                                 const unsigned short* __restrict__ mbf,
                                                 float* __restrict__ out) {
    const int nbk  = blockIdx.x;
    const int b    = blockIdx.y;
    const int t    = threadIdx.x;
    const int w    = t >> 6;
    const int l    = t & 63;
    const int g    = l >> 4;     // k-octet / row-quad selector
    const int col  = l & 15;     // n-col within tile / A-row

    const int n0 = nbk * 256 + w * 64;
    const float* xb = x + (size_t)b * CHW_;

    // --- A-fragments: M rows, [ct][ks], 16B contiguous loads (L2-hot) ---
    bf16x8 afr[4][2];
    const unsigned short* mb = mbf + (size_t)b * 4096;
    #pragma unroll
    for (int ct = 0; ct < 4; ct++)
        #pragma unroll
        for (int ks = 0; ks < 2; ks++)
            afr[ct][ks] = *(const bf16x8*)(mb + (16 * ct + col) * 64 + 32 * ks + 8 * g);

    f32x4v acc[4][4];   // [ct][nt]
    #pragma unroll
    for (int ct = 0; ct < 4; ct++)
        #pragma unroll
        for (int nt = 0; nt < 4; nt++)
            acc[ct][nt] = (f32x4v)(0.f);

    #pragma unroll
    for (int nt = 0; nt < 4; nt++) {
        const float* xpf = xb + n0 + 16 * nt + col;   // + d*HW per element
        float xv[2][8];
        #pragma unroll
        for (int ks = 0; ks < 2; ks++)
            #pragma unroll
            for (int j = 0; j < 8; j++)
                xv[ks][j] = xpf[(size_t)(32 * ks + 8 * g + j) * HW_];

        bf16x8 bfr[2];
        #pragma unroll
        for (int ks = 0; ks < 2; ks++)
            #pragma unroll
            for (int j = 0; j < 8; j++)
                bfr[ks][j] = (short)bfrne(xv[ks][j]);

        #pragma unroll
        for (int ct = 0; ct < 4; ct++)
            #pragma unroll
            for (int ks = 0; ks < 2; ks++)
                acc[ct][nt] = __builtin_amdgcn_mfma_f32_16x16x32_bf16(
                    afr[ct][ks], bfr[ks], acc[ct][nt], 0, 0, 0);
    }

    // --- store: D[row=16*ct+4*g+r][col=n0+16*nt+col] ---
    float* ob = out + (size_t)b * CHW_;
    #pragma unroll
    for (int ct = 0; ct < 4; ct++)
        #pragma unroll
        for (int nt = 0; nt < 4; nt++)
            #pragma unroll
            for (int r = 0; r < 4; r++)
                ob[(size_t)(16 * ct + 4 * g + r) * HW_ + n0 + 16 * nt + col] =
                    acc[ct][nt][r];
}

// ---------------------------------------------------------------------------
extern "C" void kernel_launch(void* const* d_in, const int* in_sizes, int n_in,
                              void* d_out, int out_size, void* d_ws, size_t ws_size,
                              hipStream_t stream) {
    const float* x = (const float*)d_in[0];
    float* out = (float*)d_out;

    float* wsf              = (float*)d_ws;
    unsigned short* mbf     = (unsigned short*)wsf;      // B*4096 ushorts (128KB)
    float* partial          = wsf + (size_t)B_ * 4096;   // B*nch*4096 floats

    int nch = 128;
    while (nch > 1) {
        size_t need = (size_t)B_ * 4096 * sizeof(float)
                    + (size_t)B_ * nch * 4096 * sizeof(float);
        if (need <= ws_size) break;
        nch >>= 1;
    }
    const int nb = HW_ / nch;

    k1_gram<<<dim3(nch, B_), 256, 0, stream>>>(x, partial, nch, nb);
    k2_softmax<<<dim3(C_, B_), 256, 0, stream>>>(partial, mbf, nch);
    k3_out<<<dim3(HW_ / 256, B_), 256, 0, stream>>>(x, mbf, out);
}

// Round 9
// 227.470 us; speedup vs baseline: 6.2830x; 1.1513x over previous
//
#include <hip/hip_runtime.h>

#define B_   16
#define C_   64
#define HW_  65536
#define CHW_ (C_ * HW_)   // 4194304 elements per batch

typedef short bf16x8 __attribute__((ext_vector_type(8)));
typedef float f32x4v __attribute__((ext_vector_type(4)));

// fp32 -> bf16 round-to-nearest-even
__device__ __forceinline__ unsigned short bfrne(float f) {
    unsigned int u = __float_as_uint(f);
    u += 0x7FFFu + ((u >> 16) & 1u);
    return (unsigned short)(u >> 16);
}
__device__ __forceinline__ float bfdec(unsigned short h) {
    return __uint_as_float((unsigned int)h << 16);
}

// ---------------------------------------------------------------------------
// Kernel 1 v4 (split-bf16 MFMA): S[b,c,d] = sum_n A[c][n]*B[n][d],
// A[c][n]=x[c*HW+n], B[n][d]=x[n*64+d].  x = hi + lo (bf16 each);
// S ~= hi*hi + hi*lo + lo*hi (3 MFMAs, fp32 accum; dropped lo*lo ~1e-2 logit
// noise).  Each wave: full 64x64 S over its n-quarter, fragments loaded
// direct-to-register in the 16x16x32 layout (validated end-to-end by k3 v6).
// Epilogue: 4-wave LDS reduce -> fp32 partial per block.
// ---------------------------------------------------------------------------
__global__ __launch_bounds__(256, 2) void k1_gram(const float* __restrict__ x,
                                                  float* __restrict__ partial,
                                                  int nch, int nb) {
    const int ch  = blockIdx.x;
    const int b   = blockIdx.y;
    const int t   = threadIdx.x;
    const int w   = t >> 6;
    const int l   = t & 63;
    const int g   = l >> 4;      // k-octet selector
    const int col = l & 15;      // A-row / B-col within 16-tile

    const float* xb = x + (size_t)b * CHW_;
    const int nq  = nb >> 2;     // n per wave
    const int nw0 = ch * nb + w * nq;

    f32x4v acc[4][4];            // [ct][dt]
    #pragma unroll
    for (int ct = 0; ct < 4; ct++)
        #pragma unroll
        for (int dt = 0; dt < 4; dt++) acc[ct][dt] = (f32x4v)(0.f);

    for (int ns = nw0; ns < nw0 + nq; ns += 32) {
        // --- A fragments: lane holds A[16ct+col][ns+8g+j], j=0..7 ---
        bf16x8 ahi[4], alo[4];
        #pragma unroll
        for (int ct = 0; ct < 4; ct++) {
            const float* ap = xb + (size_t)(16 * ct + col) * HW_ + ns + 8 * g;
            float av[8];
            *(float4*)&av[0] = *(const float4*)ap;
            *(float4*)&av[4] = *(const float4*)(ap + 4);
            #pragma unroll
            for (int j = 0; j < 8; j++) {
                const unsigned short h = bfrne(av[j]);
                ahi[ct][j] = (short)h;
                alo[ct][j] = (short)bfrne(av[j] - bfdec(h));
            }
        }
        // --- B fragments: lane holds B[ns+8g+j][16dt+col], j=0..7 ---
        bf16x8 bhi[4], blo[4];
        #pragma unroll
        for (int dt = 0; dt < 4; dt++) {
            const float* bp = xb + (size_t)(ns + 8 * g) * C_ + 16 * dt + col;
            float bv[8];
            #pragma unroll
            for (int j = 0; j < 8; j++) bv[j] = bp[j * C_];
            #pragma unroll
            for (int j = 0; j < 8; j++) {
                const unsigned short h = bfrne(bv[j]);
                bhi[dt][j] = (short)h;
                blo[dt][j] = (short)bfrne(bv[j] - bfdec(h));
            }
        }
        // --- 48 MFMAs: hi*hi + hi*lo + lo*hi ---
        #pragma unroll
        for (int ct = 0; ct < 4; ct++)
            #pragma unroll
            for (int dt = 0; dt < 4; dt++) {
                acc[ct][dt] = __builtin_amdgcn_mfma_f32_16x16x32_bf16(
                    ahi[ct], bhi[dt], acc[ct][dt], 0, 0, 0);
                acc[ct][dt] = __builtin_amdgcn_mfma_f32_16x16x32_bf16(
                    ahi[ct], blo[dt], acc[ct][dt], 0, 0, 0);
                acc[ct][dt] = __builtin_amdgcn_mfma_f32_16x16x32_bf16(
                    alo[ct], bhi[dt], acc[ct][dt], 0, 0, 0);
            }
    }

    // --- cross-wave reduce: D[16ct+4g+r][16dt+col] ---
    __shared__ float sred[4096];
    for (int wr = 0; wr < 4; wr++) {
        if (w == wr) {
            #pragma unroll
            for (int ct = 0; ct < 4; ct++)
                #pragma unroll
                for (int dt = 0; dt < 4; dt++)
                    #pragma unroll
                    for (int r = 0; r < 4; r++) {
                        const int idx = (16 * ct + 4 * g + r) * 64 + 16 * dt + col;
                        if (wr == 0) sred[idx] = acc[ct][dt][r];
                        else         sred[idx] += acc[ct][dt][r];
                    }
        }
        __syncthreads();
    }

    float* pb = partial + (size_t)(b * nch + ch) * 4096;
    for (int i = 4 * t; i < 4096; i += 1024)
        *(float4*)&pb[i] = *(const float4*)&sred[i];
}

// ---------------------------------------------------------------------------
// Kernel 2 v3: reduce partials + softmax (unchanged from R8).
// Writes mbf[b,c,d] = bf16( softmax(S)[b,c,d] + (c==d) ).
// ---------------------------------------------------------------------------
__global__ __launch_bounds__(256) void k2_softmax(const float* __restrict__ partial,
                                                  unsigned short* __restrict__ mbf,
                                                  int nch) {
    const int c = blockIdx.x;
    const int b = blockIdx.y;
    const int t = threadIdx.x;
    const int w = t >> 6;
    const int d = t & 63;

    float s = 0.f;
    for (int ch = w; ch < nch; ch += 4)
        s += partial[(size_t)(b * nch + ch) * 4096 + c * 64 + d];

    __shared__ float red[256];
    red[t] = s;
    __syncthreads();
    if (w == 0) {
        s = red[d] + red[64 + d] + red[128 + d] + red[192 + d];
        float m = s;
        #pragma unroll
        for (int off = 32; off > 0; off >>= 1) m = fmaxf(m, __shfl_xor(m, off));
        const float e = expf(s - m);
        float sum = e;
        #pragma unroll
        for (int off = 32; off > 0; off >>= 1) sum += __shfl_xor(sum, off);
        mbf[(size_t)b * 4096 + c * 64 + d] = bfrne(e / sum + (c == d ? 1.f : 0.f));
    }
}

// ---------------------------------------------------------------------------
// Kernel 3 v6 (MFMA bf16, unchanged from R8 — validated):
// out[b,c,n] = sum_d M[c,d] * X[b, d*HW + n]
// ---------------------------------------------------------------------------
__global__ __launch_bounds__(256, 3) void k3_out(const float* __restrict__ x,
                                                 const unsigned short* __restrict__ mbf,
                                                 float* __restrict__ out) {
    const int nbk  = blockIdx.x;
    const int b    = blockIdx.y;
    const int t    = threadIdx.x;
    const int w    = t >> 6;
    const int l    = t & 63;
    const int g    = l >> 4;
    const int col  = l & 15;

    const int n0 = nbk * 256 + w * 64;
    const float* xb = x + (size_t)b * CHW_;

    bf16x8 afr[4][2];
    const unsigned short* mb = mbf + (size_t)b * 4096;
    #pragma unroll
    for (int ct = 0; ct < 4; ct++)
        #pragma unroll
        for (int ks = 0; ks < 2; ks++)
            afr[ct][ks] = *(const bf16x8*)(mb + (16 * ct + col) * 64 + 32 * ks + 8 * g);

    f32x4v acc[4][4];   // [ct][nt]
    #pragma unroll
    for (int ct = 0; ct < 4; ct++)
        #pragma unroll
        for (int nt = 0; nt < 4; nt++)
            acc[ct][nt] = (f32x4v)(0.f);

    #pragma unroll
    for (int nt = 0; nt < 4; nt++) {
        const float* xpf = xb + n0 + 16 * nt + col;
        float xv[2][8];
        #pragma unroll
        for (int ks = 0; ks < 2; ks++)
            #pragma unroll
            for (int j = 0; j < 8; j++)
                xv[ks][j] = xpf[(size_t)(32 * ks + 8 * g + j) * HW_];

        bf16x8 bfr[2];
        #pragma unroll
        for (int ks = 0; ks < 2; ks++)
            #pragma unroll
            for (int j = 0; j < 8; j++)
                bfr[ks][j] = (short)bfrne(xv[ks][j]);

        #pragma unroll
        for (int ct = 0; ct < 4; ct++)
            #pragma unroll
            for (int ks = 0; ks < 2; ks++)
                acc[ct][nt] = __builtin_amdgcn_mfma_f32_16x16x32_bf16(
                    afr[ct][ks], bfr[ks], acc[ct][nt], 0, 0, 0);
    }

    float* ob = out + (size_t)b * CHW_;
    #pragma unroll
    for (int ct = 0; ct < 4; ct++)
        #pragma unroll
        for (int nt = 0; nt < 4; nt++)
            #pragma unroll
            for (int r = 0; r < 4; r++)
                ob[(size_t)(16 * ct + 4 * g + r) * HW_ + n0 + 16 * nt + col] =
                    acc[ct][nt][r];
}

// ---------------------------------------------------------------------------
extern "C" void kernel_launch(void* const* d_in, const int* in_sizes, int n_in,
                              void* d_out, int out_size, void* d_ws, size_t ws_size,
                              hipStream_t stream) {
    const float* x = (const float*)d_in[0];
    float* out = (float*)d_out;

    float* wsf          = (float*)d_ws;
    unsigned short* mbf = (unsigned short*)wsf;      // B*4096 ushorts (128KB)
    float* partial      = wsf + (size_t)B_ * 4096;   // B*nch*4096 floats

    int nch = 64;
    while (nch > 1) {
        size_t need = (size_t)B_ * 4096 * sizeof(float)
                    + (size_t)B_ * nch * 4096 * sizeof(float);
        if (need <= ws_size) break;
        nch >>= 1;
    }
    const int nb = HW_ / nch;

    k1_gram<<<dim3(nch, B_), 256, 0, stream>>>(x, partial, nch, nb);
    k2_softmax<<<dim3(C_, B_), 256, 0, stream>>>(partial, mbf, nch);
    k3_out<<<dim3(HW_ / 256, B_), 256, 0, stream>>>(x, mbf, out);
}